// Round 8
// baseline (1894.889 us; speedup 1.0000x reference)
//
#include <hip/hip_runtime.h>
#include <stdint.h>

// Problem constants
#define BATCH 128
#define LFULL 4096
#define TT 48            // number of tags
#define NPOT 4094        // pot timesteps (L-2)
#define NBP  4093        // number of bp entries / stored state vectors
#define SEG  64          // backtrack segment length
#define NSEG 64          // ceil(NBP/SEG)
#define SLOT 192         // bytes per state slot (48 floats)

// ---------------------------------------------------------------------------
// K1: forward Viterbi scan (values only). TWO chains (batches) per wave,
// software-pipelined ("skewed"): each chain's step computes from REGISTERS
// (read-ahead rd[12] float4), writes its LDS buffer, then immediately issues
// the read-back for the NEXT step. The read-back's ~250cy LDS latency hides
// under the OTHER chain's ~200cy compute. No barriers anywhere in the loop
// (per-wave LDS ops are in-order; same-buffer aliasing orders write->read;
// validated empirically in R5-R7, absmax 0).
//  - tcol[48] pinned via a LOOP-CARRIED opaque asm at the loop BOTTOM:
//    iteration N's uses read values defined by iteration N-1's asm, so
//    reloading from trans[] can never satisfy the dataflow (R6/R7's top-of-
//    loop pin was legally circumvented by reload-before-asm; VGPR stuck 60).
//  - 64 blocks x 1 wave; VGPR target ~170 (2x48 rd + 48 tcol + misc).
// Stores s_0..s_4092 into the pot region of d_out (scratch); writes
// last_tag byte into bound[b][NSEG].
__global__ __launch_bounds__(64, 1) void k_forward(const float* __restrict__ in,
                                                   const float* __restrict__ trans,
                                                   char* __restrict__ statesBase,
                                                   unsigned char* __restrict__ bound) {
    const int lane = threadIdx.x;
    const int kk = (lane < TT) ? lane : 0;
    const int bA = blockIdx.x * 2;
    const int bB = bA + 1;

    __shared__ __align__(16) float lsw[2][64];   // one buffer per chain

    // tcol[j] = T[j][kk]; coalesced (lanes consecutive for fixed j).
    float tcol[TT];
#pragma unroll
    for (int j = 0; j < TT; ++j) tcol[j] = trans[j * TT + kk];

#define PIN_TCOL() \
    asm volatile("" \
        : "+v"(tcol[0]),  "+v"(tcol[1]),  "+v"(tcol[2]),  "+v"(tcol[3]),  \
          "+v"(tcol[4]),  "+v"(tcol[5]),  "+v"(tcol[6]),  "+v"(tcol[7]),  \
          "+v"(tcol[8]),  "+v"(tcol[9]),  "+v"(tcol[10]), "+v"(tcol[11]), \
          "+v"(tcol[12]), "+v"(tcol[13]), "+v"(tcol[14]), "+v"(tcol[15]), \
          "+v"(tcol[16]), "+v"(tcol[17]), "+v"(tcol[18]), "+v"(tcol[19]), \
          "+v"(tcol[20]), "+v"(tcol[21]), "+v"(tcol[22]), "+v"(tcol[23]), \
          "+v"(tcol[24]), "+v"(tcol[25]), "+v"(tcol[26]), "+v"(tcol[27]), \
          "+v"(tcol[28]), "+v"(tcol[29]), "+v"(tcol[30]), "+v"(tcol[31]), \
          "+v"(tcol[32]), "+v"(tcol[33]), "+v"(tcol[34]), "+v"(tcol[35]), \
          "+v"(tcol[36]), "+v"(tcol[37]), "+v"(tcol[38]), "+v"(tcol[39]), \
          "+v"(tcol[40]), "+v"(tcol[41]), "+v"(tcol[42]), "+v"(tcol[43]), \
          "+v"(tcol[44]), "+v"(tcol[45]), "+v"(tcol[46]), "+v"(tcol[47]))

    PIN_TCOL();   // values enter the loop as opaque asm outputs

    const float* inA = in + (size_t)bA * (LFULL * TT);
    const float* inB = in + (size_t)bB * (LFULL * TT);
    char* sA = statesBase + (size_t)bA * NBP * SLOT;
    char* sB = statesBase + (size_t)bB * NBP * SLOT;

    // Read-ahead state registers: rd*[j] holds s_{t-1}[4j..4j+3], replicated
    // in every lane. Initialized with s0 = pot[:,0,:] = in[:,1,:] (uniform
    // float4 global reads).
    float4 rdA[12], rdB[12];
#pragma unroll
    for (int j = 0; j < 12; ++j) {
        rdA[j] = *(const float4*)(inA + TT + 4 * j);
        rdB[j] = *(const float4*)(inB + TT + 4 * j);
    }
    // store s_0 snapshots (slot 0)
    if (lane < TT) {
        ((float*)sA)[lane] = inA[TT + lane];
        ((float*)sB)[lane] = inB[TT + lane];
    }

    // One chain step: compute snew from rd regs, write LDS, snapshot,
    // then read-back rd for the next step (latency hidden by other chain).
    auto STEP = [&](int c, float4* rd, char* sb, int t, float e) {
        // 12 groups of 4: adds + group max (exact: max is assoc/comm)
        float g0, g1, g2, g3, g4, g5, g6, g7, g8, g9, g10, g11;
        {
            float a, b2, c2, d;
#define GRP(i, dst) \
            a  = rd[i].x + tcol[4*i+0]; \
            b2 = rd[i].y + tcol[4*i+1]; \
            c2 = rd[i].z + tcol[4*i+2]; \
            d  = rd[i].w + tcol[4*i+3]; \
            dst = fmaxf(fmaxf(a, b2), fmaxf(c2, d));
            GRP(0, g0)  GRP(1, g1)  GRP(2, g2)  GRP(3, g3)
            GRP(4, g4)  GRP(5, g5)  GRP(6, g6)  GRP(7, g7)
            GRP(8, g8)  GRP(9, g9)  GRP(10, g10) GRP(11, g11)
#undef GRP
        }
        float n0 = fmaxf(fmaxf(g0, g1), g2);     // max3-fusable
        float n1 = fmaxf(fmaxf(g3, g4), g5);
        float n2 = fmaxf(fmaxf(g6, g7), g8);
        float n3 = fmaxf(fmaxf(g9, g10), g11);
        float snew = fmaxf(fmaxf(n0, n1), fmaxf(n2, n3)) + e;

        lsw[c][lane] = snew;                     // ds_write (in-order queue)
        if (t <= NBP - 1 && lane < TT)           // snapshot (fire-and-forget)
            *(float*)(sb + (size_t)t * SLOT + (size_t)lane * 4) = snew;
        // read-back for next step; latency spans the other chain's compute
#pragma unroll
        for (int j = 0; j < 12; ++j)
            rd[j] = *(const float4*)(&lsw[c][4 * j]);
    };

    // emission for step t is pot[b,t,:] = in[b,t+1,:]; clamp keeps address
    // valid — over-read values are never used.
    auto LDA = [&](int t) -> float {
        int tc = (t <= NBP) ? t : NBP;
        return inA[(size_t)(tc + 1) * TT + kk];
    };
    auto LDB = [&](int t) -> float {
        int tc = (t <= NBP) ? t : NBP;
        return inB[(size_t)(tc + 1) * TT + kk];
    };

    float eA0 = LDA(1), eA1 = LDA(2), eA2 = LDA(3), eA3 = LDA(4);
    float eB0 = LDB(1), eB1 = LDB(2), eB2 = LDB(3), eB3 = LDB(4);

    int t = 1;
    for (; t + 3 <= NBP; t += 4) {               // t = 1,5,...,4089
        STEP(0, rdA, sA, t,     eA0); eA0 = LDA(t + 4);
        STEP(1, rdB, sB, t,     eB0); eB0 = LDB(t + 4);
        STEP(0, rdA, sA, t + 1, eA1); eA1 = LDA(t + 5);
        STEP(1, rdB, sB, t + 1, eB1); eB1 = LDB(t + 5);
        STEP(0, rdA, sA, t + 2, eA2); eA2 = LDA(t + 6);
        STEP(1, rdB, sB, t + 2, eB2); eB2 = LDB(t + 6);
        STEP(0, rdA, sA, t + 3, eA3); eA3 = LDA(t + 7);
        STEP(1, rdB, sB, t + 3, eB3); eB3 = LDB(t + 7);
        PIN_TCOL();                              // loop-carried opaque def
    }
    // remainder: t = 4093 (single step per chain)
    STEP(0, rdA, sA, NBP, eA0);
    STEP(1, rdB, sB, NBP, eB0);

    // last_tag = first-index argmax of final state (rd holds s_NBP, exact)
    if (lane == 0) {
        float best = rdA[0].x; int bi = 0;
#pragma unroll
        for (int j = 0; j < 12; ++j) {
            float v;
            v = rdA[j].x; if (4*j+0 > 0 && v > best) { best = v; bi = 4*j+0; }
            v = rdA[j].y; if (v > best) { best = v; bi = 4*j+1; }
            v = rdA[j].z; if (v > best) { best = v; bi = 4*j+2; }
            v = rdA[j].w; if (v > best) { best = v; bi = 4*j+3; }
        }
        bound[bA * (NSEG + 1) + NSEG] = (unsigned char)bi;
        best = rdB[0].x; bi = 0;
#pragma unroll
        for (int j = 0; j < 12; ++j) {
            float v;
            v = rdB[j].x; if (4*j+0 > 0 && v > best) { best = v; bi = 4*j+0; }
            v = rdB[j].y; if (v > best) { best = v; bi = 4*j+1; }
            v = rdB[j].z; if (v > best) { best = v; bi = 4*j+2; }
            v = rdB[j].w; if (v > best) { best = v; bi = 4*j+3; }
        }
        bound[bB * (NSEG + 1) + NSEG] = (unsigned char)bi;
    }
#undef PIN_TCOL
}

// ---------------------------------------------------------------------------
// K2: recompute backpointers bp_i[k] = argmax_j(s_i[j] + T[j][k]) for ALL
// (b,i,k), massively parallel. One wave per (b, chunk of 16 i's). bp bytes
// overwrite the first 48 bytes of each state slot (slot owned by this wave,
// fully read before written).
#define CHUNK 16
__global__ __launch_bounds__(256) void k_bp(const float* __restrict__ trans,
                                            char* __restrict__ statesBase) {
    const int lane = threadIdx.x & 63;
    const int wv = threadIdx.x >> 6;
    const int b = blockIdx.y * 4 + wv;
    const int i0 = blockIdx.x * CHUNK;
    const int kk = (lane < TT) ? lane : 0;

    __shared__ float ldsT[TT * TT];
    for (int i = threadIdx.x; i < TT * TT; i += 256) ldsT[i] = trans[i];
    __syncthreads();

    float tcol[TT];
#pragma unroll
    for (int j = 0; j < TT; ++j) tcol[j] = ldsT[j * TT + kk];

    char* sb = statesBase + (size_t)b * NBP * SLOT;

    for (int ii = 0; ii < CHUNK; ++ii) {
        int i = i0 + ii;
        if (i >= NBP) break;                     // uniform across wave
        const float* sp = (const float*)(sb + (size_t)i * SLOT);
        float sv[TT];
#pragma unroll
        for (int j = 0; j < TT; j += 4) {
            float4 v = *(const float4*)(sp + j);
            sv[j] = v.x; sv[j+1] = v.y; sv[j+2] = v.z; sv[j+3] = v.w;
        }
        float best = sv[0] + tcol[0]; int bi = 0;
#pragma unroll
        for (int j = 1; j < TT; ++j) {
            float v = sv[j] + tcol[j];
            if (v > best) { best = v; bi = j; }  // strict > : first-index wins
        }
        if (lane < TT)
            *(unsigned char*)(sb + (size_t)i * SLOT + lane) = (unsigned char)bi;
    }
}

// ---------------------------------------------------------------------------
// K3: compose each 64-step segment of backpointer maps into one map G_s
// (tag at segment end -> tag at segment start). Lane x traces start value x.
__global__ __launch_bounds__(64) void k_compose(const char* __restrict__ statesBase,
                                                unsigned char* __restrict__ G) {
    const int s = blockIdx.x, b = blockIdx.y;
    const int i0 = s * SEG;
    const int cnt = (SEG < NBP - i0) ? SEG : (NBP - i0);
    const int lane = threadIdx.x;

    __shared__ unsigned char lbp[SEG * TT];
    const char* sb = statesBase + (size_t)b * NBP * SLOT;
    for (int ii = 0; ii < cnt; ++ii) {
        if (lane < 12)
            ((uint32_t*)lbp)[ii * 12 + lane] =
                *(const uint32_t*)(sb + (size_t)(i0 + ii) * SLOT + (size_t)lane * 4);
    }
    __syncthreads();

    if (lane < TT) {
        int M = lane;
        for (int ii = cnt - 1; ii >= 0; --ii) M = lbp[ii * TT + M];
        G[(b * NSEG + s) * TT + lane] = (unsigned char)M;
    }
}

// ---------------------------------------------------------------------------
// K4: chain across segments: boundary tag at each segment start.
__global__ void k_boundary(const unsigned char* __restrict__ G,
                           unsigned char* __restrict__ bound) {
    int b = threadIdx.x;                 // 128 threads, 1 block
    int x = bound[b * (NSEG + 1) + NSEG];
    for (int s = NSEG - 1; s >= 0; --s) {
        x = G[(b * NSEG + s) * TT + x];
        bound[b * (NSEG + 1) + s] = x;
    }
}

// ---------------------------------------------------------------------------
// K5: fill tags within each segment by re-walking its bp maps from the known
// entering boundary tag. Writes final float tags.
__global__ __launch_bounds__(64) void k_fill(const char* __restrict__ statesBase,
                                             const unsigned char* __restrict__ bound,
                                             float* __restrict__ tags) {
    const int s = blockIdx.x, b = blockIdx.y;
    const int i0 = s * SEG;
    const int cnt = (SEG < NBP - i0) ? SEG : (NBP - i0);
    const int lane = threadIdx.x;

    __shared__ unsigned char lbp[SEG * TT];
    const char* sb = statesBase + (size_t)b * NBP * SLOT;
    for (int ii = 0; ii < cnt; ++ii) {
        if (lane < 12)
            ((uint32_t*)lbp)[ii * 12 + lane] =
                *(const uint32_t*)(sb + (size_t)(i0 + ii) * SLOT + (size_t)lane * 4);
    }
    __syncthreads();

    if (lane == 0) {
        int x = bound[b * (NSEG + 1) + s + 1];   // tag at position (s+1)*SEG (or last_tag)
        if (s == NSEG - 1)
            tags[(size_t)b * NPOT + (NPOT - 1)] = (float)x;
        for (int ii = cnt - 1; ii >= 0; --ii) {
            x = lbp[ii * TT + x];
            tags[(size_t)b * NPOT + i0 + ii] = (float)x;
        }
    }
}

// ---------------------------------------------------------------------------
// K6: final copies — pot = in[:,1:-1,:] and transitions passthrough.
__global__ __launch_bounds__(256) void k_copy(const float* __restrict__ in,
                                              const float* __restrict__ trans,
                                              float* __restrict__ out) {
    const int potN4 = (BATCH * NPOT * TT) / 4;   // 6,288,384 float4s
    const int rowN = NPOT * TT;                  // 196,512
    int idx = blockIdx.x * 256 + threadIdx.x;
    if (idx < potN4) {
        int p4 = idx * 4;
        int b = p4 / rowN;
        int off = p4 - b * rowN;
        float4 v = *(const float4*)(in + (size_t)b * (LFULL * TT) + off + TT);
        *(float4*)(out + p4) = v;
    } else if (idx < potN4 + (TT * TT) / 4) {
        int q = idx - potN4;
        *(float4*)(out + (size_t)BATCH * NPOT * TT + (size_t)q * 4) =
            *(const float4*)(trans + (size_t)q * 4);
    }
}

// ---------------------------------------------------------------------------
extern "C" void kernel_launch(void* const* d_in, const int* in_sizes, int n_in,
                              void* d_out, int out_size, void* d_ws, size_t ws_size,
                              hipStream_t stream) {
    (void)in_sizes; (void)n_in; (void)d_ws; (void)ws_size; (void)out_size;

    const float* in = (const float*)d_in[0];
    const float* trans = (const float*)d_in[1];
    float* out = (float*)d_out;

    // Scratch carved out of d_out (stream-ordered so everything is rewritten):
    //  - pot region   [0 .. 100.6MB): state vectors, then bp bytes in-place
    //  - trans region [2304 floats]: boundary tags (128 x 65 bytes)
    //  - tags region  [524032 floats]: segment maps G, then final tags
    char* statesBase = (char*)d_out;
    unsigned char* bound = (unsigned char*)(out + (size_t)BATCH * NPOT * TT);
    unsigned char* G = (unsigned char*)(out + (size_t)BATCH * NPOT * TT + TT * TT);
    float* tags = out + (size_t)BATCH * NPOT * TT + TT * TT;

    k_forward <<<dim3(BATCH / 2),    dim3(64),  0, stream>>>(in, trans, statesBase, bound);
    k_bp      <<<dim3(256, 32),      dim3(256), 0, stream>>>(trans, statesBase);
    k_compose <<<dim3(NSEG, BATCH),  dim3(64),  0, stream>>>(statesBase, G);
    k_boundary<<<dim3(1),            dim3(BATCH), 0, stream>>>(G, bound);
    k_fill    <<<dim3(NSEG, BATCH),  dim3(64),  0, stream>>>(statesBase, bound, tags);

    int total4 = (BATCH * NPOT * TT) / 4 + (TT * TT) / 4;
    k_copy    <<<dim3((total4 + 255) / 256), dim3(256), 0, stream>>>(in, trans, out);
}

// Round 9
// 1185.171 us; speedup vs baseline: 1.5988x; 1.5988x over previous
//
#include <hip/hip_runtime.h>
#include <stdint.h>

// Problem constants
#define BATCH 128
#define LFULL 4096
#define TT 48            // number of tags
#define NPOT 4094        // pot timesteps (L-2)
#define NBP  4093        // number of bp entries / stored state vectors
#define SEG  64          // backtrack segment length
#define NSEG 64          // ceil(NBP/SEG)
#define SLOT 192         // bytes per state slot (48 floats)

// ---------------------------------------------------------------------------
__device__ __forceinline__ float rdlane(float v, int l) {
    return __int_as_float(__builtin_amdgcn_readlane(__float_as_int(v), l));
}

// ---------------------------------------------------------------------------
// K1: forward Viterbi scan (values only). One wave per batch, 128 blocks.
// ZERO-MEMORY broadcast: the state vector lives as 48 UNIFORM values
// (SGPRs). Per step, each lane k computes cand[j] = s[j] + tcol[j]
// (v_add_f32 with one SGPR operand -- legal), reduces with a max3 tree,
// adds its emission, then the wave re-collects the 48 lane-scalars with
// 48 v_readlane (pure register traffic, ~2cy each). No LDS, no barriers,
// no memory latency on the serial chain -- it is issue-bound (~125 instr).
//  - tcol[48] pinned via the loop-carried bottom-of-loop opaque asm
//    (proven effective in R8: VGPR went 60->88 with tcol resident).
//  - Snapshot stores are fire-and-forget (1 coalesced 192B store/step);
//    lanes 48-63 duplicate lane 0's store (same addr, same value) to avoid
//    per-step exec-mask toggling.
// Stores s_0..s_4092 into the pot region of d_out (scratch); writes
// last_tag byte into bound[b][NSEG].
__global__ __launch_bounds__(64, 1) void k_forward(const float* __restrict__ in,
                                                   const float* __restrict__ trans,
                                                   char* __restrict__ statesBase,
                                                   unsigned char* __restrict__ bound) {
    const int b = blockIdx.x;
    const int lane = threadIdx.x;
    const int kk = (lane < TT) ? lane : 0;

    // tcol[j] = T[j][kk]; coalesced (lanes consecutive for fixed j).
    float tcol[TT];
#pragma unroll
    for (int j = 0; j < TT; ++j) tcol[j] = trans[j * TT + kk];

#define PIN_TCOL() \
    asm volatile("" \
        : "+v"(tcol[0]),  "+v"(tcol[1]),  "+v"(tcol[2]),  "+v"(tcol[3]),  \
          "+v"(tcol[4]),  "+v"(tcol[5]),  "+v"(tcol[6]),  "+v"(tcol[7]),  \
          "+v"(tcol[8]),  "+v"(tcol[9]),  "+v"(tcol[10]), "+v"(tcol[11]), \
          "+v"(tcol[12]), "+v"(tcol[13]), "+v"(tcol[14]), "+v"(tcol[15]), \
          "+v"(tcol[16]), "+v"(tcol[17]), "+v"(tcol[18]), "+v"(tcol[19]), \
          "+v"(tcol[20]), "+v"(tcol[21]), "+v"(tcol[22]), "+v"(tcol[23]), \
          "+v"(tcol[24]), "+v"(tcol[25]), "+v"(tcol[26]), "+v"(tcol[27]), \
          "+v"(tcol[28]), "+v"(tcol[29]), "+v"(tcol[30]), "+v"(tcol[31]), \
          "+v"(tcol[32]), "+v"(tcol[33]), "+v"(tcol[34]), "+v"(tcol[35]), \
          "+v"(tcol[36]), "+v"(tcol[37]), "+v"(tcol[38]), "+v"(tcol[39]), \
          "+v"(tcol[40]), "+v"(tcol[41]), "+v"(tcol[42]), "+v"(tcol[43]), \
          "+v"(tcol[44]), "+v"(tcol[45]), "+v"(tcol[46]), "+v"(tcol[47]))

    PIN_TCOL();

    const float* inb = in + (size_t)b * (LFULL * TT);
    char* sb = statesBase + (size_t)b * NBP * SLOT;

    // s0 = pot[b,0,:] = in[b,1,:]; collect into uniform state s[48].
    float s[TT];
    {
        float v0 = inb[TT + kk];
        *(float*)(sb + (size_t)kk * 4) = v0;           // snapshot s_0 (dup lanes ok)
#pragma unroll
        for (int j = 0; j < TT; ++j) s[j] = rdlane(v0, j);
    }

    // exact 48-way max, max3-shaped: 16 + 5 + 2 + 1 = 24 instrs
    auto MAX48 = [](const float* c) -> float {
        float g[16];
#pragma unroll
        for (int i = 0; i < 16; ++i)
            g[i] = fmaxf(fmaxf(c[3*i], c[3*i+1]), c[3*i+2]);
        float h0 = fmaxf(fmaxf(g[0], g[1]), g[2]);
        float h1 = fmaxf(fmaxf(g[3], g[4]), g[5]);
        float h2 = fmaxf(fmaxf(g[6], g[7]), g[8]);
        float h3 = fmaxf(fmaxf(g[9], g[10]), g[11]);
        float h4 = fmaxf(fmaxf(g[12], g[13]), g[14]);
        float m0 = fmaxf(fmaxf(h0, h1), h2);
        float m1 = fmaxf(fmaxf(h3, h4), g[15]);
        return fmaxf(m0, m1);
    };

    // one Viterbi step: snew[k] = max_j(s[j]+T[j][k]) + e; re-collect.
    auto STEP = [&](int t, float e) {
        float c[TT];
#pragma unroll
        for (int j = 0; j < TT; ++j) c[j] = s[j] + tcol[j];
        float snew = MAX48(c) + e;
        if (t <= NBP - 1)                        // snapshot s_t (t<=4092)
            *(float*)(sb + (size_t)t * SLOT + (size_t)kk * 4) = snew;
#pragma unroll
        for (int j = 0; j < TT; ++j) s[j] = rdlane(snew, j);
    };

    // emission for step t is pot[b,t,:] = in[b,t+1,:]; clamp keeps address
    // valid (over-read values are never used).
    auto LD = [&](int t) -> float {
        int tc = (t <= NBP) ? t : NBP;
        return inb[(size_t)(tc + 1) * TT + kk];
    };

    float e0 = LD(1), e1 = LD(2), e2 = LD(3), e3 = LD(4);
    float e4 = LD(5), e5 = LD(6), e6 = LD(7), e7 = LD(8);
    int t = 1;
    for (; t + 7 <= NBP; t += 8) {               // t = 1, 9, ..., 4081
        STEP(t,     e0); e0 = LD(t + 8);
        STEP(t + 1, e1); e1 = LD(t + 9);
        STEP(t + 2, e2); e2 = LD(t + 10);
        STEP(t + 3, e3); e3 = LD(t + 11);
        STEP(t + 4, e4); e4 = LD(t + 12);
        STEP(t + 5, e5); e5 = LD(t + 13);
        STEP(t + 6, e6); e6 = LD(t + 14);
        STEP(t + 7, e7); e7 = LD(t + 15);
        PIN_TCOL();                              // loop-carried opaque def
    }
    // tail: t = 4089..4093
    STEP(4089, e0);
    STEP(4090, e1);
    STEP(4091, e2);
    STEP(4092, e3);
    STEP(4093, e4);

    // last_tag = first-index argmax of final state (s[] uniform, exact)
    if (lane == 0) {
        float best = s[0]; int bi = 0;
#pragma unroll
        for (int j = 1; j < TT; ++j) {
            if (s[j] > best) { best = s[j]; bi = j; }
        }
        bound[b * (NSEG + 1) + NSEG] = (unsigned char)bi;
    }
#undef PIN_TCOL
}

// ---------------------------------------------------------------------------
// K2: recompute backpointers bp_i[k] = argmax_j(s_i[j] + T[j][k]) for ALL
// (b,i,k), massively parallel. One wave per (b, chunk of 16 i's). bp bytes
// overwrite the first 48 bytes of each state slot (slot owned by this wave,
// fully read before written).
#define CHUNK 16
__global__ __launch_bounds__(256) void k_bp(const float* __restrict__ trans,
                                            char* __restrict__ statesBase) {
    const int lane = threadIdx.x & 63;
    const int wv = threadIdx.x >> 6;
    const int b = blockIdx.y * 4 + wv;
    const int i0 = blockIdx.x * CHUNK;
    const int kk = (lane < TT) ? lane : 0;

    __shared__ float ldsT[TT * TT];
    for (int i = threadIdx.x; i < TT * TT; i += 256) ldsT[i] = trans[i];
    __syncthreads();

    float tcol[TT];
#pragma unroll
    for (int j = 0; j < TT; ++j) tcol[j] = ldsT[j * TT + kk];

    char* sb = statesBase + (size_t)b * NBP * SLOT;

    for (int ii = 0; ii < CHUNK; ++ii) {
        int i = i0 + ii;
        if (i >= NBP) break;                     // uniform across wave
        const float* sp = (const float*)(sb + (size_t)i * SLOT);
        float sv[TT];
#pragma unroll
        for (int j = 0; j < TT; j += 4) {
            float4 v = *(const float4*)(sp + j);
            sv[j] = v.x; sv[j+1] = v.y; sv[j+2] = v.z; sv[j+3] = v.w;
        }
        float best = sv[0] + tcol[0]; int bi = 0;
#pragma unroll
        for (int j = 1; j < TT; ++j) {
            float v = sv[j] + tcol[j];
            if (v > best) { best = v; bi = j; }  // strict > : first-index wins
        }
        if (lane < TT)
            *(unsigned char*)(sb + (size_t)i * SLOT + lane) = (unsigned char)bi;
    }
}

// ---------------------------------------------------------------------------
// K3: compose each 64-step segment of backpointer maps into one map G_s
// (tag at segment end -> tag at segment start). Lane x traces start value x.
__global__ __launch_bounds__(64) void k_compose(const char* __restrict__ statesBase,
                                                unsigned char* __restrict__ G) {
    const int s = blockIdx.x, b = blockIdx.y;
    const int i0 = s * SEG;
    const int cnt = (SEG < NBP - i0) ? SEG : (NBP - i0);
    const int lane = threadIdx.x;

    __shared__ unsigned char lbp[SEG * TT];
    const char* sb = statesBase + (size_t)b * NBP * SLOT;
    for (int ii = 0; ii < cnt; ++ii) {
        if (lane < 12)
            ((uint32_t*)lbp)[ii * 12 + lane] =
                *(const uint32_t*)(sb + (size_t)(i0 + ii) * SLOT + (size_t)lane * 4);
    }
    __syncthreads();

    if (lane < TT) {
        int M = lane;
        for (int ii = cnt - 1; ii >= 0; --ii) M = lbp[ii * TT + M];
        G[(b * NSEG + s) * TT + lane] = (unsigned char)M;
    }
}

// ---------------------------------------------------------------------------
// K4: chain across segments: boundary tag at each segment start.
__global__ void k_boundary(const unsigned char* __restrict__ G,
                           unsigned char* __restrict__ bound) {
    int b = threadIdx.x;                 // 128 threads, 1 block
    int x = bound[b * (NSEG + 1) + NSEG];
    for (int s = NSEG - 1; s >= 0; --s) {
        x = G[(b * NSEG + s) * TT + x];
        bound[b * (NSEG + 1) + s] = x;
    }
}

// ---------------------------------------------------------------------------
// K5: fill tags within each segment by re-walking its bp maps from the known
// entering boundary tag. Writes final float tags.
__global__ __launch_bounds__(64) void k_fill(const char* __restrict__ statesBase,
                                             const unsigned char* __restrict__ bound,
                                             float* __restrict__ tags) {
    const int s = blockIdx.x, b = blockIdx.y;
    const int i0 = s * SEG;
    const int cnt = (SEG < NBP - i0) ? SEG : (NBP - i0);
    const int lane = threadIdx.x;

    __shared__ unsigned char lbp[SEG * TT];
    const char* sb = statesBase + (size_t)b * NBP * SLOT;
    for (int ii = 0; ii < cnt; ++ii) {
        if (lane < 12)
            ((uint32_t*)lbp)[ii * 12 + lane] =
                *(const uint32_t*)(sb + (size_t)(i0 + ii) * SLOT + (size_t)lane * 4);
    }
    __syncthreads();

    if (lane == 0) {
        int x = bound[b * (NSEG + 1) + s + 1];   // tag at position (s+1)*SEG (or last_tag)
        if (s == NSEG - 1)
            tags[(size_t)b * NPOT + (NPOT - 1)] = (float)x;
        for (int ii = cnt - 1; ii >= 0; --ii) {
            x = lbp[ii * TT + x];
            tags[(size_t)b * NPOT + i0 + ii] = (float)x;
        }
    }
}

// ---------------------------------------------------------------------------
// K6: final copies — pot = in[:,1:-1,:] and transitions passthrough.
__global__ __launch_bounds__(256) void k_copy(const float* __restrict__ in,
                                              const float* __restrict__ trans,
                                              float* __restrict__ out) {
    const int potN4 = (BATCH * NPOT * TT) / 4;   // 6,288,384 float4s
    const int rowN = NPOT * TT;                  // 196,512
    int idx = blockIdx.x * 256 + threadIdx.x;
    if (idx < potN4) {
        int p4 = idx * 4;
        int b = p4 / rowN;
        int off = p4 - b * rowN;
        float4 v = *(const float4*)(in + (size_t)b * (LFULL * TT) + off + TT);
        *(float4*)(out + p4) = v;
    } else if (idx < potN4 + (TT * TT) / 4) {
        int q = idx - potN4;
        *(float4*)(out + (size_t)BATCH * NPOT * TT + (size_t)q * 4) =
            *(const float4*)(trans + (size_t)q * 4);
    }
}

// ---------------------------------------------------------------------------
extern "C" void kernel_launch(void* const* d_in, const int* in_sizes, int n_in,
                              void* d_out, int out_size, void* d_ws, size_t ws_size,
                              hipStream_t stream) {
    (void)in_sizes; (void)n_in; (void)d_ws; (void)ws_size; (void)out_size;

    const float* in = (const float*)d_in[0];
    const float* trans = (const float*)d_in[1];
    float* out = (float*)d_out;

    // Scratch carved out of d_out (stream-ordered so everything is rewritten):
    //  - pot region   [0 .. 100.6MB): state vectors, then bp bytes in-place
    //  - trans region [2304 floats]: boundary tags (128 x 65 bytes)
    //  - tags region  [524032 floats]: segment maps G, then final tags
    char* statesBase = (char*)d_out;
    unsigned char* bound = (unsigned char*)(out + (size_t)BATCH * NPOT * TT);
    unsigned char* G = (unsigned char*)(out + (size_t)BATCH * NPOT * TT + TT * TT);
    float* tags = out + (size_t)BATCH * NPOT * TT + TT * TT;

    k_forward <<<dim3(BATCH),        dim3(64),  0, stream>>>(in, trans, statesBase, bound);
    k_bp      <<<dim3(256, 32),      dim3(256), 0, stream>>>(trans, statesBase);
    k_compose <<<dim3(NSEG, BATCH),  dim3(64),  0, stream>>>(statesBase, G);
    k_boundary<<<dim3(1),            dim3(BATCH), 0, stream>>>(G, bound);
    k_fill    <<<dim3(NSEG, BATCH),  dim3(64),  0, stream>>>(statesBase, bound, tags);

    int total4 = (BATCH * NPOT * TT) / 4 + (TT * TT) / 4;
    k_copy    <<<dim3((total4 + 255) / 256), dim3(256), 0, stream>>>(in, trans, out);
}